// Round 11
// baseline (1057.004 us; speedup 1.0000x reference)
//
#include <hip/hip_runtime.h>

typedef _Float16 half_t;
typedef _Float16 half8  __attribute__((ext_vector_type(8)));
typedef _Float16 half4v __attribute__((ext_vector_type(4)));
typedef float    f32x4  __attribute__((ext_vector_type(4)));

#define SCALE  0.17677669529663687f

// ---- prep: weights f32->f16 (q_w pre-scaled); fused bias+mask in FRAG-MAJOR order
// fusedF[cls][head][(nt*4+mt)*256 + lane*4 + r] = bias+mask at i=nt*16+l15, j=mt*16+g*4+r
__global__ __launch_bounds__(256) void swin_prep(
    const float* __restrict__ q_w, const float* __restrict__ kv_w,
    const float* __restrict__ proj_w, const float* __restrict__ rpb,
    const float* __restrict__ mask,
    half_t* __restrict__ w16, half_t* __restrict__ fusedF)
{
    int t = blockIdx.x * 256 + threadIdx.x;
    if (t < 65536)        w16[t] = (half_t)(q_w[t] * SCALE);
    else if (t < 196608)  w16[t] = (half_t)kv_w[t - 65536];
    else if (t < 262144)  w16[t] = (half_t)proj_w[t - 196608];
    else if (t < 393216) {
        int u = t - 262144;                 // [0, 131072)
        int cls = u >> 15, q = u & 32767;
        int h = q >> 12, s = q & 4095;
        int nt = s >> 10, mt = (s >> 8) & 3, lane = (s >> 2) & 63, r = s & 3;
        int g = lane >> 4, l15 = lane & 15;
        int i = nt * 16 + l15, j = mt * 16 + g * 4 + r;
        int idx = ((i >> 3) - (j >> 3) + 7) * 15 + ((i & 7) - (j & 7) + 7);
        int wsel = (cls == 0) ? 0 : (cls == 1) ? 31 : (cls == 2) ? 992 : 1023;
        fusedF[u] = (half_t)(rpb[idx * 8 + h] + mask[(size_t)wsel * 4096 + i * 64 + j]);
    }
}

static __device__ __forceinline__ unsigned pk2(float a, float b) {
    union { _Float16 h[2]; unsigned u; } t;
    t.h[0] = (_Float16)a; t.h[1] = (_Float16)b; return t.u;
}
static __device__ __forceinline__ half8 cvt8(float4 a, float4 b) {
    half8 h;
    h[0] = (half_t)a.x; h[1] = (half_t)a.y; h[2] = (half_t)a.z; h[3] = (half_t)a.w;
    h[4] = (half_t)b.x; h[5] = (half_t)b.y; h[6] = (half_t)b.z; h[7] = (half_t)b.w;
    return h;
}

// C-layout (contraction axis on g*4+r over two 16-tiles) -> A/B-frag (contraction
// axis on g*8+e), l15 axis preserved; verified R2-R10.
#define BUILD_FRAG(dst, P0, P1)                                          \
    do {                                                                 \
        union { unsigned u[4]; half8 h; } _u;                            \
        _Pragma("unroll")                                                \
        for (int p = 0; p < 4; ++p) {                                    \
            int _src = (p >> 1) ? srcB : srcA;                           \
            unsigned _rlo = (unsigned)__shfl((int)(P0)[p & 1], _src);    \
            unsigned _rhi = (unsigned)__shfl((int)(P1)[p & 1], _src);    \
            _u.u[p] = hi ? _rhi : _rlo;                                  \
        }                                                                \
        dst = _u.h;                                                      \
    } while (0)

// ================= fused: one window per block, zero staging, one barrier =================
__global__ __launch_bounds__(512, 2) void swin_fused(
    const float* __restrict__ x, const float* __restrict__ y,
    const float* __restrict__ q_b, const float* __restrict__ kv_b,
    const float* __restrict__ proj_b,
    const half_t* __restrict__ w16, const half_t* __restrict__ fusedF,
    float* __restrict__ out)
{
    __shared__ __align__(16) half_t Osm[16384];   // 32 KB: O frag exchange [hc*4+mt][lane*8]
    const int tid  = threadIdx.x;
    const int w    = tid >> 6;       // wave = head
    const int lane = tid & 63;
    const int l15  = lane & 15;
    const int g    = lane >> 4;
    const int b    = blockIdx.x;
    const int jf0  = w * 32;
    const int srcA = ((2 * g) & 3) * 16 + l15;
    const int srcB = ((2 * g + 1) & 3) * 16 + l15;
    const int hi   = g >> 1;
    const half_t* wkv = w16 + 65536;
    const half_t* wpj = w16 + 196608;

    const float* xb = x + (size_t)b * 16384;
    const float* yb = y + (size_t)b * 16384;

    // ---- Phase A: K^T, V from y (direct strided loads + cvt; no LDS) ----
    f32x4 kacc[2][4], vacc[4][2];
    #pragma unroll
    for (int ft = 0; ft < 2; ++ft)
        #pragma unroll
        for (int tok = 0; tok < 4; ++tok) {
            f32x4 z = {0.f,0.f,0.f,0.f}; kacc[ft][tok] = z; vacc[tok][ft] = z;
        }
    #pragma unroll
    for (int kh = 0; kh < 8; ++kh) {
        int k0 = kh * 32 + g * 8;
        half8 wk[2], wv[2], a[4];
        #pragma unroll
        for (int ft = 0; ft < 2; ++ft) {
            int jf = jf0 + ft * 16 + l15;
            wk[ft] = *(const half8*)(wkv + jf * 256 + k0);
            wv[ft] = *(const half8*)(wkv + (256 + jf) * 256 + k0);
        }
        #pragma unroll
        for (int tok = 0; tok < 4; ++tok) {
            const float* s = yb + (tok * 16 + l15) * 256 + k0;
            a[tok] = cvt8(*(const float4*)s, *(const float4*)(s + 4));
        }
        #pragma unroll
        for (int ft = 0; ft < 2; ++ft)
            #pragma unroll
            for (int tok = 0; tok < 4; ++tok) {
                kacc[ft][tok] = __builtin_amdgcn_mfma_f32_16x16x32_f16(wk[ft], a[tok], kacc[ft][tok], 0, 0, 0);
                vacc[tok][ft] = __builtin_amdgcn_mfma_f32_16x16x32_f16(a[tok], wv[ft], vacc[tok][ft], 0, 0, 0);
            }
    }
    // pack K^T (+bias, feature on g*4+r) and V (+bias, feature on l15)
    unsigned kp[2][4][2], vp[4][2][2];
    #pragma unroll
    for (int ft = 0; ft < 2; ++ft) {
        float4 kb4 = *(const float4*)(kv_b + jf0 + ft * 16 + g * 4);
        float  vb  = kv_b[256 + jf0 + ft * 16 + l15];
        #pragma unroll
        for (int tok = 0; tok < 4; ++tok) {
            kp[ft][tok][0] = pk2(kacc[ft][tok][0] + kb4.x, kacc[ft][tok][1] + kb4.y);
            kp[ft][tok][1] = pk2(kacc[ft][tok][2] + kb4.z, kacc[ft][tok][3] + kb4.w);
            vp[tok][ft][0] = pk2(vacc[tok][ft][0] + vb, vacc[tok][ft][1] + vb);
            vp[tok][ft][1] = pk2(vacc[tok][ft][2] + vb, vacc[tok][ft][3] + vb);
        }
    }

    // ---- Phase B: Q^T from x (direct) ----
    unsigned qp[2][4][2];
    {
        f32x4 qacc[2][4];
        #pragma unroll
        for (int ft = 0; ft < 2; ++ft)
            #pragma unroll
            for (int tok = 0; tok < 4; ++tok) { f32x4 z = {0.f,0.f,0.f,0.f}; qacc[ft][tok] = z; }
        #pragma unroll
        for (int kh = 0; kh < 8; ++kh) {
            int k0 = kh * 32 + g * 8;
            half8 wq[2], a[4];
            #pragma unroll
            for (int ft = 0; ft < 2; ++ft)
                wq[ft] = *(const half8*)(w16 + (jf0 + ft * 16 + l15) * 256 + k0);
            #pragma unroll
            for (int tok = 0; tok < 4; ++tok) {
                const float* s = xb + (tok * 16 + l15) * 256 + k0;
                a[tok] = cvt8(*(const float4*)s, *(const float4*)(s + 4));
            }
            #pragma unroll
            for (int ft = 0; ft < 2; ++ft)
                #pragma unroll
                for (int tok = 0; tok < 4; ++tok)
                    qacc[ft][tok] = __builtin_amdgcn_mfma_f32_16x16x32_f16(wq[ft], a[tok], qacc[ft][tok], 0, 0, 0);
        }
        #pragma unroll
        for (int ft = 0; ft < 2; ++ft) {
            float4 q4 = *(const float4*)(q_b + jf0 + ft * 16 + g * 4);
            #pragma unroll
            for (int tok = 0; tok < 4; ++tok) {
                qp[ft][tok][0] = pk2(qacc[ft][tok][0] + q4.x * SCALE, qacc[ft][tok][1] + q4.y * SCALE);
                qp[ft][tok][1] = pk2(qacc[ft][tok][2] + q4.z * SCALE, qacc[ft][tok][3] + q4.w * SCALE);
            }
        }
    }

    // ---- Phase C: attention, all in registers (verified R5/R10) ----
    f32x4 o[2][4];
    {
        half8 ka[4], qf[4];
        #pragma unroll
        for (int mt = 0; mt < 4; ++mt) BUILD_FRAG(ka[mt], kp[0][mt], kp[1][mt]);
        #pragma unroll
        for (int nt = 0; nt < 4; ++nt) BUILD_FRAG(qf[nt], qp[0][nt], qp[1][nt]);

        f32x4 t[4][4];
        #pragma unroll
        for (int mt = 0; mt < 4; ++mt)
            #pragma unroll
            for (int nt = 0; nt < 4; ++nt) {
                f32x4 z = {0.f,0.f,0.f,0.f};
                t[mt][nt] = __builtin_amdgcn_mfma_f32_16x16x32_f16(ka[mt], qf[nt], z, 0, 0, 0);
            }

        // fused bias+mask, frag-major coalesced (verified R10)
        const int wi = b & 1023;
        const int cls = ((((wi >> 5) == 31) ? 2 : 0)) | (((wi & 31) == 31) ? 1 : 0);
        const half_t* fb = fusedF + ((size_t)cls * 8 + w) * 4096;
        half4v fm[4][4];
        #pragma unroll
        for (int nt = 0; nt < 4; ++nt)
            #pragma unroll
            for (int mt = 0; mt < 4; ++mt)
                fm[nt][mt] = *(const half4v*)(fb + (nt * 4 + mt) * 256 + lane * 4);

        #pragma unroll
        for (int nt = 0; nt < 4; ++nt) {
            #pragma unroll
            for (int mt = 0; mt < 4; ++mt)
                #pragma unroll
                for (int r = 0; r < 4; ++r)
                    t[mt][nt][r] += (float)fm[nt][mt][r];
            float m = -1e30f;
            #pragma unroll
            for (int mt = 0; mt < 4; ++mt)
                #pragma unroll
                for (int r = 0; r < 4; ++r) m = fmaxf(m, t[mt][nt][r]);
            m = fmaxf(m, __shfl_xor(m, 16));
            m = fmaxf(m, __shfl_xor(m, 32));
            float s = 0.f;
            #pragma unroll
            for (int mt = 0; mt < 4; ++mt)
                #pragma unroll
                for (int r = 0; r < 4; ++r) {
                    float p = __expf(t[mt][nt][r] - m);
                    t[mt][nt][r] = p;
                    s += p;
                }
            s += __shfl_xor(s, 16);
            s += __shfl_xor(s, 32);
            float inv = 1.f / s;
            #pragma unroll
            for (int mt = 0; mt < 4; ++mt)
                #pragma unroll
                for (int r = 0; r < 4; ++r) t[mt][nt][r] *= inv;
        }

        unsigned pp[4][4][2];
        #pragma unroll
        for (int mt = 0; mt < 4; ++mt)
            #pragma unroll
            for (int nt = 0; nt < 4; ++nt) {
                pp[mt][nt][0] = pk2(t[mt][nt][0], t[mt][nt][1]);
                pp[mt][nt][1] = pk2(t[mt][nt][2], t[mt][nt][3]);
            }

        #pragma unroll
        for (int dt = 0; dt < 2; ++dt)
            #pragma unroll
            for (int nt = 0; nt < 4; ++nt) { f32x4 z = {0.f,0.f,0.f,0.f}; o[dt][nt] = z; }
        #pragma unroll
        for (int kc = 0; kc < 2; ++kc) {
            half8 va[2], pf[4];
            #pragma unroll
            for (int dt = 0; dt < 2; ++dt) BUILD_FRAG(va[dt], vp[kc*2+0][dt], vp[kc*2+1][dt]);
            #pragma unroll
            for (int nt = 0; nt < 4; ++nt) BUILD_FRAG(pf[nt], pp[kc*2+0][nt], pp[kc*2+1][nt]);
            #pragma unroll
            for (int dt = 0; dt < 2; ++dt)
                #pragma unroll
                for (int nt = 0; nt < 4; ++nt)
                    o[dt][nt] = __builtin_amdgcn_mfma_f32_16x16x32_f16(va[dt], pf[nt], o[dt][nt], 0, 0, 0);
        }
    }

    // ---- O frag exchange via LDS (linear b128, conflict-free); single barrier ----
    {
        unsigned po[2][4][2];
        #pragma unroll
        for (int dt = 0; dt < 2; ++dt)
            #pragma unroll
            for (int nt = 0; nt < 4; ++nt) {
                po[dt][nt][0] = pk2(o[dt][nt][0], o[dt][nt][1]);
                po[dt][nt][1] = pk2(o[dt][nt][2], o[dt][nt][3]);
            }
        #pragma unroll
        for (int nt = 0; nt < 4; ++nt) {
            half8 f;
            BUILD_FRAG(f, po[0][nt], po[1][nt]);
            *(half8*)(Osm + (w * 4 + nt) * 512 + lane * 8) = f;
        }
    }
    __syncthreads();

    // ---- Phase D: out = O @ proj_w^T + proj_b (verified R9/R10 K3 structure) ----
    {
        f32x4 dacc[4][2];   // token on l15, jf on g*4+r
        #pragma unroll
        for (int mt = 0; mt < 4; ++mt)
            #pragma unroll
            for (int ft = 0; ft < 2; ++ft) { f32x4 z = {0.f,0.f,0.f,0.f}; dacc[mt][ft] = z; }
        #pragma unroll
        for (int hc = 0; hc < 8; ++hc) {
            int k0 = hc * 32 + g * 8;
            half8 wbp[2], a[4];
            #pragma unroll
            for (int ft = 0; ft < 2; ++ft)
                wbp[ft] = *(const half8*)(wpj + (jf0 + ft * 16 + l15) * 256 + k0);
            #pragma unroll
            for (int mt = 0; mt < 4; ++mt)
                a[mt] = *(const half8*)(Osm + (hc * 4 + mt) * 512 + lane * 8);
            #pragma unroll
            for (int mt = 0; mt < 4; ++mt)
                #pragma unroll
                for (int ft = 0; ft < 2; ++ft)
                    dacc[mt][ft] = __builtin_amdgcn_mfma_f32_16x16x32_f16(wbp[ft], a[mt], dacc[mt][ft], 0, 0, 0);
        }
        float* ob = out + (size_t)b * 16384;
        #pragma unroll
        for (int ft = 0; ft < 2; ++ft) {
            float4 pb4 = *(const float4*)(proj_b + jf0 + ft * 16 + g * 4);
            #pragma unroll
            for (int mt = 0; mt < 4; ++mt) {
                f32x4 v;
                v[0] = dacc[mt][ft][0] + pb4.x;
                v[1] = dacc[mt][ft][1] + pb4.y;
                v[2] = dacc[mt][ft][2] + pb4.z;
                v[3] = dacc[mt][ft][3] + pb4.w;
                *(f32x4*)(ob + (mt * 16 + l15) * 256 + jf0 + ft * 16 + g * 4) = v;
            }
        }
    }
}

extern "C" void kernel_launch(void* const* d_in, const int* in_sizes, int n_in,
                              void* d_out, int out_size, void* d_ws, size_t ws_size,
                              hipStream_t stream) {
    const float* x      = (const float*)d_in[0];
    const float* y      = (const float*)d_in[1];
    const float* mask   = (const float*)d_in[2];
    const float* q_w    = (const float*)d_in[3];
    const float* q_b    = (const float*)d_in[4];
    const float* kv_w   = (const float*)d_in[5];
    const float* kv_b   = (const float*)d_in[6];
    const float* proj_w = (const float*)d_in[7];
    const float* proj_b = (const float*)d_in[8];
    const float* rpb    = (const float*)d_in[9];
    float* out          = (float*)d_out;

    half_t* w16    = (half_t*)d_ws;                      // 512KB
    half_t* fusedF = (half_t*)((char*)d_ws + 524288);    // 256KB

    swin_prep<<<1536, 256, 0, stream>>>(q_w, kv_w, proj_w, rpb, mask, w16, fusedF);
    swin_fused<<<4096, 512, 0, stream>>>(x, y, q_b, kv_b, proj_b, w16, fusedF, out);
}